// Round 1
// baseline (150.748 us; speedup 1.0000x reference)
//
#include <hip/hip_runtime.h>

#define D   512
#define NB1 256
#define NB2 512
#define NL  3

// ---------------- normalize rows: dst[r,:] = src[r,:] / max(||src[r,:]||, 1e-12)
__global__ __launch_bounds__(256) void norm_rows_kernel(const float* __restrict__ src,
                                                        float* __restrict__ dst,
                                                        int rows) {
    int gw = (blockIdx.x * blockDim.x + threadIdx.x) >> 6;
    int lane = threadIdx.x & 63;
    if (gw >= rows) return;
    const float* r = src + (size_t)gw * D;
    float v[8];
    float s = 0.f;
#pragma unroll
    for (int i = 0; i < 8; ++i) {
        v[i] = r[i * 64 + lane];
        s += v[i] * v[i];
    }
#pragma unroll
    for (int off = 32; off; off >>= 1) s += __shfl_xor(s, off);
    float nrm = fmaxf(sqrtf(s), 1e-12f);
    float inv = 1.f / nrm;
    float* w = dst + (size_t)gw * D;
#pragma unroll
    for (int i = 0; i < 8; ++i) w[i * 64 + lane] = v[i] * inv;
}

// ---------------- top-3 per column of links[l], column-normalized.
// one wave (block of 64) per (l, e). widx[l*D+e] = packed 3x9-bit row indices,
// wval[(l*D+e)*3 + k] = value_k / (sum of top3 + 1e-8)
__global__ __launch_bounds__(64) void topk_kernel(const float* __restrict__ links,
                                                  unsigned int* __restrict__ widx,
                                                  float* __restrict__ wval) {
    int gw = blockIdx.x;          // 0 .. 2*D-1
    int lane = threadIdx.x;       // 0 .. 63
    int l = gw >> 9;
    int e = gw & (D - 1);
    const float* base = links + (size_t)l * D * D + e;
    float v[8];
#pragma unroll
    for (int i = 0; i < 8; ++i) v[i] = base[(size_t)(i * 64 + lane) * D];
    float mv[3];
    int mi[3];
    for (int k = 0; k < 3; ++k) {
        float lm = -1.f;            // links are uniform[0,1): all >= 0
        int li = 0x7fffffff;
#pragma unroll
        for (int i = 0; i < 8; ++i) {
            if (v[i] > lm) { lm = v[i]; li = i * 64 + lane; }
        }
#pragma unroll
        for (int off = 32; off; off >>= 1) {
            float ov = __shfl_xor(lm, off);
            int oi = __shfl_xor(li, off);
            if (ov > lm || (ov == lm && oi < li)) { lm = ov; li = oi; }
        }
        mv[k] = lm;
        mi[k] = li;
        if (li < D && (li & 63) == lane) v[li >> 6] = -1.f;  // consume
    }
    if (lane == 0) {
        float s = mv[0] + mv[1] + mv[2] + 1e-8f;
        float invs = 1.f / s;
        widx[gw] = (unsigned)mi[0] | ((unsigned)mi[1] << 9) | ((unsigned)mi[2] << 18);
        wval[gw * 3 + 0] = mv[0] * invs;
        wval[gw * 3 + 1] = mv[1] * invs;
        wval[gw * 3 + 2] = mv[2] * invs;
    }
}

// ---------------- fused main kernel: one wave per (b, n-chunk of 32)
__global__ __launch_bounds__(256) void avsl_main_kernel(
    const float* __restrict__ n1,     // (3,B1,D) normalized emb1
    const float* __restrict__ n2,     // (3,B2,D) normalized emb2
    const float* __restrict__ cert1,  // (3,B1,D)
    const float* __restrict__ cert2,  // (3,B2,D)
    const unsigned* __restrict__ widx,// (2,D) packed
    const float* __restrict__ wval,   // (2,D,3)
    const float* __restrict__ alpha,  // (2,D)
    const float* __restrict__ beta,   // (2,D)
    float* __restrict__ out)          // (B1,B2)
{
    __shared__ float vbuf[4][2][D];   // per-wave private {v0, v1}
    const int lane = threadIdx.x & 63;
    const int wid = threadIdx.x >> 6;
    const int gw = blockIdx.x * 4 + wid;   // 0 .. 4095
    const int b = gw >> 4;                 // 0 .. 255
    const int n0 = (gw & 15) * 32;

    // preload per-b data and sparse-W tables into registers; lane owns e = i*64+lane
    float a0[8], a1r[8], a2r[8], ac1[8], ac2[8], bt1[8], bt2[8];
    float w1a[8], w1b[8], w1c[8], w2a[8], w2b[8], w2c[8];
    unsigned id1[8], id2[8];
#pragma unroll
    for (int i = 0; i < 8; ++i) {
        int e = i * 64 + lane;
        a0[i]  = n1[(0 * NB1 + b) * D + e];
        a1r[i] = n1[(1 * NB1 + b) * D + e];
        a2r[i] = n1[(2 * NB1 + b) * D + e];
        ac1[i] = alpha[e]     * cert1[(1 * NB1 + b) * D + e];
        ac2[i] = alpha[D + e] * cert1[(2 * NB1 + b) * D + e];
        bt1[i] = beta[e];
        bt2[i] = beta[D + e];
        id1[i] = widx[e];
        id2[i] = widx[D + e];
        w1a[i] = wval[e * 3 + 0];
        w1b[i] = wval[e * 3 + 1];
        w1c[i] = wval[e * 3 + 2];
        w2a[i] = wval[(D + e) * 3 + 0];
        w2b[i] = wval[(D + e) * 3 + 1];
        w2c[i] = wval[(D + e) * 3 + 2];
    }
    float* v0 = vbuf[wid][0];
    float* v1 = vbuf[wid][1];

    for (int nn = 0; nn < 32; ++nn) {
        int n = n0 + nn;
        const float* r0 = n2 + (size_t)(0 * NB2 + n) * D;
        const float* r1 = n2 + (size_t)(1 * NB2 + n) * D;
        const float* r2 = n2 + (size_t)(2 * NB2 + n) * D;
        const float* c1 = cert2 + (size_t)(1 * NB2 + n) * D;
        const float* c2 = cert2 + (size_t)(2 * NB2 + n) * D;

        // layer 0: v0[e] = (e1_0[b,e] - e2_0[n,e])^2
#pragma unroll
        for (int i = 0; i < 8; ++i) {
            int e = i * 64 + lane;
            float d0 = a0[i] - r0[e];
            v0[e] = d0 * d0;
        }
        // layer 1: v1[e] = (1-P)*gather3(v0) + P*node
#pragma unroll
        for (int i = 0; i < 8; ++i) {
            int e = i * 64 + lane;
            unsigned p = id1[i];
            float g = w1a[i] * v0[p & 511] + w1b[i] * v0[(p >> 9) & 511] +
                      w1c[i] * v0[(p >> 18) & 511];
            float t = ac1[i] * c1[e] + bt1[i];
            float P = 1.f / (1.f + __expf(-t));
            float dd = a1r[i] - r1[e];
            float node = dd * dd;
            v1[e] = g + P * (node - g);
        }
        // layer 2 + final sum over e
        float acc = 0.f;
#pragma unroll
        for (int i = 0; i < 8; ++i) {
            int e = i * 64 + lane;
            unsigned p = id2[i];
            float g = w2a[i] * v1[p & 511] + w2b[i] * v1[(p >> 9) & 511] +
                      w2c[i] * v1[(p >> 18) & 511];
            float t = ac2[i] * c2[e] + bt2[i];
            float P = 1.f / (1.f + __expf(-t));
            float dd = a2r[i] - r2[e];
            float node = dd * dd;
            acc += g + P * (node - g);
        }
#pragma unroll
        for (int off = 32; off; off >>= 1) acc += __shfl_xor(acc, off);
        if (lane == 0) out[b * NB2 + n] = acc;
    }
}

extern "C" void kernel_launch(void* const* d_in, const int* in_sizes, int n_in,
                              void* d_out, int out_size, void* d_ws, size_t ws_size,
                              hipStream_t stream) {
    const float* emb1  = (const float*)d_in[0];  // (3,256,512)
    const float* cert1 = (const float*)d_in[1];  // (3,256,512)
    const float* emb2  = (const float*)d_in[2];  // (3,512,512)
    const float* cert2 = (const float*)d_in[3];  // (3,512,512)
    const float* links = (const float*)d_in[4];  // (2,512,512)
    const float* alpha = (const float*)d_in[5];  // (2,512)
    const float* beta  = (const float*)d_in[6];  // (2,512)
    float* out = (float*)d_out;                  // (256,512)

    float* n1 = (float*)d_ws;                    // 3*256*512 f32
    float* n2 = n1 + NL * NB1 * D;               // 3*512*512 f32
    unsigned* widx = (unsigned*)(n2 + NL * NB2 * D); // 2*512 u32
    float* wval = (float*)(widx + 2 * D);        // 2*512*3 f32

    hipLaunchKernelGGL(norm_rows_kernel, dim3((NL * NB1) / 4), dim3(256), 0, stream,
                       emb1, n1, NL * NB1);
    hipLaunchKernelGGL(norm_rows_kernel, dim3((NL * NB2) / 4), dim3(256), 0, stream,
                       emb2, n2, NL * NB2);
    hipLaunchKernelGGL(topk_kernel, dim3(2 * D), dim3(64), 0, stream,
                       links, widx, wval);
    hipLaunchKernelGGL(avsl_main_kernel, dim3(1024), dim3(256), 0, stream,
                       n1, n2, cert1, cert2, widx, wval, alpha, beta, out);
}